// Round 2
// baseline (288.347 us; speedup 1.0000x reference)
//
#include <hip/hip_runtime.h>
#include <math.h>

// Problem constants (from reference setup_inputs)
#define BB 16
#define LL 64
#define FF 60
#define DD 256
#define UU 600
#define VV 10000
#define JMAX 10
#define MINL 4
#define EE 7           // MAX_LEN - MIN_LEN + 1
#define NEG (-1e9f)
#define TH 0.05f

// Workspace layout (in floats). Total ~= 4.62 MB.
#define UNT_OFF   0                         // unT[256][640]  (u padded 600->640)
#define UNT_SZ    (256 * 640)
#define WNT_OFF   (UNT_OFF + UNT_SZ)        // wnT[256][1024] (bl = b*64+l)
#define WNT_SZ    (256 * 1024)
#define SIM_OFF   (WNT_OFF + WNT_SZ)        // sim[16][64][600]
#define SIM_SZ    (BB * LL * UU)
#define SEGT_OFF  (SIM_OFF + SIM_SZ)        // int segT[10][10000]
#define SEGT_SZ   (JMAX * VV)
#define VAL_OFF   (SEGT_OFF + SEGT_SZ)      // val[16][64][7]
#define VAL_SZ    (BB * LL * EE)
#define VOC_OFF   (VAL_OFF + VAL_SZ)        // int voc[16][64][7]

// ---------------------------------------------------------------------------
// Transpose indexed_segments [V][J] -> segT [J][V] so phase-3 reads coalesce.
__global__ __launch_bounds__(256) void k_segT(const int* __restrict__ seg,
                                              int* __restrict__ segT) {
    int idx = blockIdx.x * 256 + threadIdx.x;
    if (idx < VV * JMAX) {
        int v = idx / JMAX;
        int j = idx - v * JMAX;
        segT[j * VV + v] = seg[idx];
    }
}

// ---------------------------------------------------------------------------
// Embed + L2-normalize rows of unit_feats (600) and x (1024), storing both
// TRANSPOSED: unT[d][u] (stride 640), wnT[d][bl] (stride 1024). One wave per
// row; lane covers 4 of the 256 output dims.
__global__ __launch_bounds__(64) void k_embed(const float* __restrict__ x,
                                              const float* __restrict__ uf,
                                              const float* __restrict__ W,
                                              float* __restrict__ unT,
                                              float* __restrict__ wnT) {
    int id = blockIdx.x;
    int lane = threadIdx.x;
    const float* row;
    float* outB;
    int stride, col;
    if (id < UU) { row = uf + id * FF; outB = unT; stride = 640;  col = id; }
    else { int bl = id - UU; row = x + bl * FF; outB = wnT; stride = 1024; col = bl; }

    float r0 = 0.f, r1 = 0.f, r2 = 0.f, r3 = 0.f;
    for (int f = 0; f < FF; ++f) {
        float xv = row[f];  // wave-uniform broadcast load
        r0 += xv * W[f * DD + lane];
        r1 += xv * W[f * DD + lane + 64];
        r2 += xv * W[f * DD + lane + 128];
        r3 += xv * W[f * DD + lane + 192];
    }
    float ss = r0 * r0 + r1 * r1 + r2 * r2 + r3 * r3;
#pragma unroll
    for (int m = 32; m > 0; m >>= 1) ss += __shfl_xor(ss, m, 64);
    float inv = 1.0f / (sqrtf(ss) + 1e-8f);   // matches ref x/(norm+1e-8)
    outB[(lane      ) * stride + col] = r0 * inv;
    outB[(lane +  64) * stride + col] = r1 * inv;
    outB[(lane + 128) * stride + col] = r2 * inv;
    outB[(lane + 192) * stride + col] = r3 * inv;
}

// ---------------------------------------------------------------------------
// sim[b][l][u] = wn[bl] . un[u].  Block = (b, 4-l tile); thread tile = 4l x 3u.
__global__ __launch_bounds__(256) void k_sim(const float* __restrict__ unT,
                                             const float* __restrict__ wnT,
                                             float* __restrict__ sim) {
    int blk = blockIdx.x;
    int b  = blk >> 4;
    int l0 = (blk & 15) * 4;
    int bl0 = b * 64 + l0;
    int w = threadIdx.x >> 6;
    int lane = threadIdx.x & 63;
    // wave -> u-chunk sets: w0:{0,1,2} w1:{3,4,5} w2:{6,7,8} w3:{8,9,(10 oob)}
    int cb = (w < 2) ? 3 * w : 2 * w + 2;
    int u0 = (cb + 0) * 64 + lane;
    int u1 = (cb + 1) * 64 + lane;
    int u2 = (cb + 2) * 64 + lane;
    int uu2 = (u2 < 640) ? u2 : 0;   // clamp: chunk-10 lanes read dummy, never stored

    float a00 = 0.f, a01 = 0.f, a02 = 0.f;
    float a10 = 0.f, a11 = 0.f, a12 = 0.f;
    float a20 = 0.f, a21 = 0.f, a22 = 0.f;
    float a30 = 0.f, a31 = 0.f, a32 = 0.f;

#pragma unroll 2
    for (int d = 0; d < DD; ++d) {
        float w0 = wnT[d * 1024 + bl0 + 0];
        float w1 = wnT[d * 1024 + bl0 + 1];
        float w2 = wnT[d * 1024 + bl0 + 2];
        float w3 = wnT[d * 1024 + bl0 + 3];
        float v0 = unT[d * 640 + u0];
        float v1 = unT[d * 640 + u1];
        float v2 = unT[d * 640 + uu2];
        a00 += w0 * v0; a01 += w0 * v1; a02 += w0 * v2;
        a10 += w1 * v0; a11 += w1 * v1; a12 += w1 * v2;
        a20 += w2 * v0; a21 += w2 * v1; a22 += w2 * v2;
        a30 += w3 * v0; a31 += w3 * v1; a32 += w3 * v2;
    }
    if (u0 < UU) {
        sim[(bl0 + 0) * UU + u0] = a00; sim[(bl0 + 1) * UU + u0] = a10;
        sim[(bl0 + 2) * UU + u0] = a20; sim[(bl0 + 3) * UU + u0] = a30;
    }
    if (u1 < UU) {
        sim[(bl0 + 0) * UU + u1] = a01; sim[(bl0 + 1) * UU + u1] = a11;
        sim[(bl0 + 2) * UU + u1] = a21; sim[(bl0 + 3) * UU + u1] = a31;
    }
    if (u2 < UU) {  // wave2 t2 duplicates wave3 t0 with identical values (benign)
        sim[(bl0 + 0) * UU + u2] = a02; sim[(bl0 + 1) * UU + u2] = a12;
        sim[(bl0 + 2) * UU + u2] = a22; sim[(bl0 + 3) * UU + u2] = a32;
    }
}

// ---------------------------------------------------------------------------
// Phase 3: per (b, l-pair) block. Stage sim rows l0..l0+10 in LDS transposed
// [u][11] (stride 11: coprime with 32 banks). For each v: prefix-sum gathered
// sims along its unit sequence; snapshot at k==j+1 into statically-indexed
// per-length best regs (strict > keeps lowest v). Then hierarchical reduce.
__global__ __launch_bounds__(256) void k_score(const float* __restrict__ sim,
                                               const int* __restrict__ segT,
                                               const int* __restrict__ vlen,
                                               const int* __restrict__ lengths,
                                               float* __restrict__ val,
                                               int* __restrict__ voc) {
    __shared__ float lds[UU * 11];   // 26.4 KB
    __shared__ float redS[14][4];    // e*2+dl in [0,14)
    __shared__ int   redV[14][4];

    int blk = blockIdx.x;
    int b  = blk >> 5;
    int l0 = (blk & 31) * 2;
    int tid = threadIdx.x;

    // Stage sim tile -> LDS transposed; rows >= L are the zero-pad region.
#pragma unroll
    for (int r = 0; r < 11; ++r) {
        int m = l0 + r;
        const float* src = sim + (b * 64 + m) * UU;
        bool inb = (m < LL);
        for (int u = tid; u < UU; u += 256) {
            lds[u * 11 + r] = inb ? src[u] : 0.0f;
        }
    }
    __syncthreads();

    float bS[EE][2];
    int   bV[EE][2];
#pragma unroll
    for (int e = 0; e < EE; ++e) {
        bS[e][0] = -1e30f; bS[e][1] = -1e30f;
        bV[e][0] = 0;      bV[e][1] = 0;
    }

    for (int v = tid; v < VV; v += 256) {
        int k = vlen[v];
        float a0 = 0.f, a1 = 0.f;
#pragma unroll
        for (int j = 0; j < JMAX; ++j) {
            if (j < k) {
                int u = segT[j * VV + v];
                int base = u * 11 + j;
                float x0 = lds[base];
                float x1 = lds[base + 1];
                a0 += x0; a1 += x1;
                if (j >= MINL - 1 && k == j + 1) {
                    // true division to match ref acc/(j+1) bit-for-bit
                    float s0 = a0 / (float)(j + 1);
                    float s1 = a1 / (float)(j + 1);
                    int e = j - (MINL - 1);                   // static per unroll
                    if (s0 > bS[e][0]) { bS[e][0] = s0; bV[e][0] = v; }
                    if (s1 > bS[e][1]) { bS[e][1] = s1; bV[e][1] = v; }
                }
            }
        }
    }

    int w = tid >> 6, lane = tid & 63;
#pragma unroll
    for (int e = 0; e < EE; ++e) {
#pragma unroll
        for (int dl = 0; dl < 2; ++dl) {
            float s = bS[e][dl];
            int vv = bV[e][dl];
#pragma unroll
            for (int off = 32; off > 0; off >>= 1) {
                float os = __shfl_down(s, off, 64);
                int   ov = __shfl_down(vv, off, 64);
                if (os > s || (os == s && ov < vv)) { s = os; vv = ov; }
            }
            if (lane == 0) { redS[e * 2 + dl][w] = s; redV[e * 2 + dl][w] = vv; }
        }
    }
    __syncthreads();

    // ONLY indices 0..13 of redS/redV are valid: guard is tid < 14 (was 28:
    // threads 14..27 wrote e=7..13 OOB into the next l-slot -> vocab corrupt).
    if (tid < 14) {
        int e  = tid >> 1;
        int dl = tid & 1;
        float s = redS[tid][0];
        int  vv = redV[tid][0];
#pragma unroll
        for (int w2 = 1; w2 < 4; ++w2) {
            float os = redS[tid][w2];
            int   ov = redV[tid][w2];
            if (os > s || (os == s && ov < vv)) { s = os; vv = ov; }
        }
        int lg = l0 + dl;
        int k = e + MINL;
        bool viable = (lg + k - 1) < lengths[b];
        val[(b * 64 + lg) * EE + e] = viable ? s : NEG;
        voc[(b * 64 + lg) * EE + e] = viable ? vv : 0;  // ref argmax of all-NEG = 0
    }
}

// ---------------------------------------------------------------------------
// Per-b: flat argmax over the 448 (l,e) slots (min flat index on ties),
// any_matched = max > THRESH. Outputs written as float32 values.
__global__ __launch_bounds__(512) void k_final(const float* __restrict__ val,
                                               const int* __restrict__ voc,
                                               float* __restrict__ out) {
    __shared__ float sS[8];
    __shared__ int   sI[8];
    __shared__ int   sA[8];
    int b = blockIdx.x;
    int t = threadIdx.x;
    float s = -3e38f;
    int idx = 1 << 30;
    int any = 0;
    if (t < LL * EE) {
        s = val[b * LL * EE + t];
        idx = t;
        any = (s > TH) ? 1 : 0;
    }
#pragma unroll
    for (int off = 32; off > 0; off >>= 1) {
        float os = __shfl_down(s, off, 64);
        int   oi = __shfl_down(idx, off, 64);
        int   oa = __shfl_down(any, off, 64);
        if (os > s || (os == s && oi < idx)) { s = os; idx = oi; }
        any |= oa;
    }
    int w = t >> 6, lane = t & 63;
    if (lane == 0) { sS[w] = s; sI[w] = idx; sA[w] = any; }
    __syncthreads();
    if (t == 0) {
        for (int w2 = 1; w2 < 8; ++w2) {
            float os = sS[w2];
            int   oi = sI[w2];
            if (os > s || (os == s && oi < idx)) { s = os; idx = oi; }
            any |= sA[w2];
        }
        int start = idx / EE;
        int e = idx - start * EE;
        int end = e + start + MINL - 1;
        int vocab = voc[b * LL * EE + idx];
        out[b]      = s;
        out[16 + b] = (float)start;
        out[32 + b] = (float)end;
        out[48 + b] = any ? 1.0f : 0.0f;
        out[64 + b] = (float)vocab;
    }
}

// ---------------------------------------------------------------------------
extern "C" void kernel_launch(void* const* d_in, const int* in_sizes, int n_in,
                              void* d_out, int out_size, void* d_ws, size_t ws_size,
                              hipStream_t stream) {
    const float* x       = (const float*)d_in[0];   // [16][64][60]
    const float* uf      = (const float*)d_in[1];   // [600][60]
    const float* W       = (const float*)d_in[2];   // [60][256]
    const int*   lengths = (const int*)d_in[3];     // [16]
    const int*   seg     = (const int*)d_in[4];     // [10000][10]
    const int*   vlen    = (const int*)d_in[5];     // [10000]
    float* out = (float*)d_out;
    float* ws  = (float*)d_ws;

    float* unT  = ws + UNT_OFF;
    float* wnT  = ws + WNT_OFF;
    float* sim  = ws + SIM_OFF;
    int*   segT = (int*)(ws + SEGT_OFF);
    float* val  = ws + VAL_OFF;
    int*   voc  = (int*)(ws + VOC_OFF);

    k_segT<<<(VV * JMAX + 255) / 256, 256, 0, stream>>>(seg, segT);
    k_embed<<<UU + BB * LL, 64, 0, stream>>>(x, uf, W, unT, wnT);
    k_sim<<<256, 256, 0, stream>>>(unT, wnT, sim);
    k_score<<<512, 256, 0, stream>>>(sim, segT, vlen, lengths, val, voc);
    k_final<<<BB, 512, 0, stream>>>(val, voc, out);
}

// Round 4
// 146.857 us; speedup vs baseline: 1.9635x; 1.9635x over previous
//
#include <hip/hip_runtime.h>
#include <math.h>

// Problem constants (from reference setup_inputs)
#define BB 16
#define LL 64
#define FF 60
#define DD 256
#define UU 600
#define VV 10000
#define JMAX 10
#define MINL 4
#define EE 7           // MAX_LEN - MIN_LEN + 1
#define NEG (-1e9f)
#define TH 0.05f

// Workspace layout (in floats). Total ~= 4.46 MB.
#define UNT_OFF   0                         // unT[256][640]  (u padded 600->640)
#define UNT_SZ    (256 * 640)
#define WNT_OFF   (UNT_OFF + UNT_SZ)        // wnT[256][1024] (bl = b*64+l)
#define WNT_SZ    (256 * 1024)
#define SIM_OFF   (WNT_OFF + WNT_SZ)        // sim[16][64][600]
#define SIM_SZ    (BB * LL * UU)
#define PK_OFF    (SIM_OFF + SIM_SZ)        // packed seg: 24B per v (6 u32)
#define PK_SZ     (VV * 6)
#define VAL_OFF   (PK_OFF + PK_SZ)          // val[16][64][7]
#define VAL_SZ    (BB * LL * EE)
#define VOC_OFF   (VAL_OFF + VAL_SZ)        // int voc[16][64][7]

// ---------------------------------------------------------------------------
// Pack per-v record: 10 x u16 precomputed LDS indices (u*11+j, max 6598),
// then u16 vlen, u16 pad. 24B per v, 8B-aligned -> 3 independent dwordx2
// loads in k_score (addresses known at v-loop head; no per-j global load).
__global__ __launch_bounds__(256) void k_pack(const int* __restrict__ seg,
                                              const int* __restrict__ vlen,
                                              unsigned int* __restrict__ pk) {
    int v = blockIdx.x * 256 + threadIdx.x;
    if (v >= VV) return;
    const int* s = seg + v * JMAX;
    unsigned int t[10];
#pragma unroll
    for (int j = 0; j < JMAX; ++j) t[j] = (unsigned int)(s[j] * 11 + j);
    unsigned int* dst = pk + v * 6;
    dst[0] = t[0] | (t[1] << 16);
    dst[1] = t[2] | (t[3] << 16);
    dst[2] = t[4] | (t[5] << 16);
    dst[3] = t[6] | (t[7] << 16);
    dst[4] = t[8] | (t[9] << 16);
    dst[5] = (unsigned int)vlen[v];
}

// ---------------------------------------------------------------------------
// Embed + L2-normalize rows of unit_feats (600) and x (1024), storing both
// TRANSPOSED: unT[d][u] (stride 640), wnT[d][bl] (stride 1024). One wave per
// row; lane covers 4 of the 256 output dims.
__global__ __launch_bounds__(64) void k_embed(const float* __restrict__ x,
                                              const float* __restrict__ uf,
                                              const float* __restrict__ W,
                                              float* __restrict__ unT,
                                              float* __restrict__ wnT) {
    int id = blockIdx.x;
    int lane = threadIdx.x;
    const float* row;
    float* outB;
    int stride, col;
    if (id < UU) { row = uf + id * FF; outB = unT; stride = 640;  col = id; }
    else { int bl = id - UU; row = x + bl * FF; outB = wnT; stride = 1024; col = bl; }

    float r0 = 0.f, r1 = 0.f, r2 = 0.f, r3 = 0.f;
#pragma unroll 4
    for (int f = 0; f < FF; ++f) {
        float xv = row[f];  // wave-uniform broadcast load
        r0 += xv * W[f * DD + lane];
        r1 += xv * W[f * DD + lane + 64];
        r2 += xv * W[f * DD + lane + 128];
        r3 += xv * W[f * DD + lane + 192];
    }
    float ss = r0 * r0 + r1 * r1 + r2 * r2 + r3 * r3;
#pragma unroll
    for (int m = 32; m > 0; m >>= 1) ss += __shfl_xor(ss, m, 64);
    float inv = 1.0f / (sqrtf(ss) + 1e-8f);   // matches ref x/(norm+1e-8)
    outB[(lane      ) * stride + col] = r0 * inv;
    outB[(lane +  64) * stride + col] = r1 * inv;
    outB[(lane + 128) * stride + col] = r2 * inv;
    outB[(lane + 192) * stride + col] = r3 * inv;
}

// ---------------------------------------------------------------------------
// sim[b][l][u] = wn[bl] . un[u].  Block = (b, 4-l tile), 512 threads (8
// waves). Waves 0..7 own u-chunks 0..7; waves 0,1 additionally own chunks
// 8,9 (tail clamped at 600).
__global__ __launch_bounds__(512, 2) void k_sim(const float* __restrict__ unT,
                                                const float* __restrict__ wnT,
                                                float* __restrict__ sim) {
    int blk = blockIdx.x;
    int b  = blk >> 4;
    int l0 = (blk & 15) * 4;
    int bl0 = b * 64 + l0;
    int tid = threadIdx.x;
    int w = tid >> 6;
    int lane = tid & 63;
    int u0 = w * 64 + lane;                 // chunks 0..7, always < 512 < 600
    bool two = (w < 2);
    int u1 = two ? (512 + w * 64 + lane) : u0;   // chunks 8,9 (<= 639, padded)

    float a00 = 0.f, a10 = 0.f, a20 = 0.f, a30 = 0.f;   // u0, l 0..3
    float a01 = 0.f, a11 = 0.f, a21 = 0.f, a31 = 0.f;   // u1, l 0..3

#pragma unroll 4
    for (int d = 0; d < DD; ++d) {
        float w0 = wnT[d * 1024 + bl0 + 0];
        float w1 = wnT[d * 1024 + bl0 + 1];
        float w2 = wnT[d * 1024 + bl0 + 2];
        float w3 = wnT[d * 1024 + bl0 + 3];
        float v0 = unT[d * 640 + u0];
        float v1 = unT[d * 640 + u1];
        a00 += w0 * v0; a01 += w0 * v1;
        a10 += w1 * v0; a11 += w1 * v1;
        a20 += w2 * v0; a21 += w2 * v1;
        a30 += w3 * v0; a31 += w3 * v1;
    }
    sim[(bl0 + 0) * UU + u0] = a00;
    sim[(bl0 + 1) * UU + u0] = a10;
    sim[(bl0 + 2) * UU + u0] = a20;
    sim[(bl0 + 3) * UU + u0] = a30;
    if (two && u1 < UU) {
        sim[(bl0 + 0) * UU + u1] = a01;
        sim[(bl0 + 1) * UU + u1] = a11;
        sim[(bl0 + 2) * UU + u1] = a21;
        sim[(bl0 + 3) * UU + u1] = a31;
    }
}

// ---------------------------------------------------------------------------
// Phase 3: per (b, l-pair) block, 512 threads. Stage sim rows l0..l0+10 in
// LDS transposed [u][11] (stride 11, coprime with 32 banks) — STRIDED loop
// so all 600 u-rows are staged (round-3 bug: if(tid<600) with 512 threads
// left u=512..599 uninitialized). Per v: 3 dwordx2 packed index loads up
// front, straight-line fully-unrolled 10-step ds_read2_b32 chain, branchless
// predicated best-updates on RAW sums (divide winner once at the end).
__global__ __launch_bounds__(512, 4) void k_score(const float* __restrict__ sim,
                                                  const unsigned int* __restrict__ pk,
                                                  const int* __restrict__ lengths,
                                                  float* __restrict__ val,
                                                  int* __restrict__ voc) {
    __shared__ float lds[UU * 11];   // 26.4 KB
    __shared__ float redS[14][8];    // e*2+dl in [0,14) x 8 waves
    __shared__ int   redV[14][8];

    int blk = blockIdx.x;
    int b  = blk >> 5;
    int l0 = (blk & 31) * 2;
    int tid = threadIdx.x;

    // Stage sim tile -> LDS transposed; rows >= L are the zero-pad region.
    for (int u = tid; u < UU; u += 512) {
#pragma unroll
        for (int r = 0; r < 11; ++r) {
            int m = l0 + r;
            lds[u * 11 + r] = (m < LL) ? sim[(b * 64 + m) * UU + u] : 0.0f;
        }
    }
    __syncthreads();

    float bS[EE][2];
    int   bV[EE][2];
#pragma unroll
    for (int e = 0; e < EE; ++e) {
        bS[e][0] = -1e30f; bS[e][1] = -1e30f;
        bV[e][0] = 0;      bV[e][1] = 0;
    }

    for (int v = tid; v < VV; v += 512) {
        const uint2* pp = (const uint2*)(pk + v * 6);
        uint2 q0 = pp[0];
        uint2 q1 = pp[1];
        uint2 q2 = pp[2];
        int idx[10];
        idx[0] = q0.x & 0xffff; idx[1] = q0.x >> 16;
        idx[2] = q0.y & 0xffff; idx[3] = q0.y >> 16;
        idx[4] = q1.x & 0xffff; idx[5] = q1.x >> 16;
        idx[6] = q1.y & 0xffff; idx[7] = q1.y >> 16;
        idx[8] = q2.x & 0xffff; idx[9] = q2.x >> 16;
        int k = (int)(q2.y & 0xffff);

        float a0 = 0.f, a1 = 0.f;
#pragma unroll
        for (int j = 0; j < JMAX; ++j) {
            float x0 = lds[idx[j]];
            float x1 = lds[idx[j] + 1];
            a0 += x0;
            a1 += x1;
            if (j >= MINL - 1) {
                int e = j - (MINL - 1);          // static after full unroll
                bool m = (k == j + 1);
                bool p0 = m & (a0 > bS[e][0]);
                bool p1 = m & (a1 > bS[e][1]);
                bS[e][0] = p0 ? a0 : bS[e][0];
                bV[e][0] = p0 ? v  : bV[e][0];
                bS[e][1] = p1 ? a1 : bS[e][1];
                bV[e][1] = p1 ? v  : bV[e][1];
            }
        }
    }

    int w = tid >> 6, lane = tid & 63;
#pragma unroll
    for (int e = 0; e < EE; ++e) {
#pragma unroll
        for (int dl = 0; dl < 2; ++dl) {
            float s = bS[e][dl];
            int vv = bV[e][dl];
#pragma unroll
            for (int off = 32; off > 0; off >>= 1) {
                float os = __shfl_down(s, off, 64);
                int   ov = __shfl_down(vv, off, 64);
                if (os > s || (os == s && ov < vv)) { s = os; vv = ov; }
            }
            if (lane == 0) { redS[e * 2 + dl][w] = s; redV[e * 2 + dl][w] = vv; }
        }
    }
    __syncthreads();

    if (tid < 14) {   // only indices 0..13 of redS/redV are valid
        int e  = tid >> 1;
        int dl = tid & 1;
        float s = redS[tid][0];
        int  vv = redV[tid][0];
#pragma unroll
        for (int w2 = 1; w2 < 8; ++w2) {
            float os = redS[tid][w2];
            int   ov = redV[tid][w2];
            if (os > s || (os == s && ov < vv)) { s = os; vv = ov; }
        }
        int lg = l0 + dl;
        int k = e + MINL;
        bool viable = (lg + k - 1) < lengths[b];
        float sn = s / (float)k;   // normalize winner only (bit-same as ref a/k)
        val[(b * 64 + lg) * EE + e] = viable ? sn : NEG;
        voc[(b * 64 + lg) * EE + e] = viable ? vv : 0;  // ref argmax of all-NEG = 0
    }
}

// ---------------------------------------------------------------------------
// Per-b: flat argmax over the 448 (l,e) slots (min flat index on ties),
// any_matched = max > THRESH. Outputs written as float32 values.
__global__ __launch_bounds__(512) void k_final(const float* __restrict__ val,
                                               const int* __restrict__ voc,
                                               float* __restrict__ out) {
    __shared__ float sS[8];
    __shared__ int   sI[8];
    __shared__ int   sA[8];
    int b = blockIdx.x;
    int t = threadIdx.x;
    float s = -3e38f;
    int idx = 1 << 30;
    int any = 0;
    if (t < LL * EE) {
        s = val[b * LL * EE + t];
        idx = t;
        any = (s > TH) ? 1 : 0;
    }
#pragma unroll
    for (int off = 32; off > 0; off >>= 1) {
        float os = __shfl_down(s, off, 64);
        int   oi = __shfl_down(idx, off, 64);
        int   oa = __shfl_down(any, off, 64);
        if (os > s || (os == s && oi < idx)) { s = os; idx = oi; }
        any |= oa;
    }
    int w = t >> 6, lane = t & 63;
    if (lane == 0) { sS[w] = s; sI[w] = idx; sA[w] = any; }
    __syncthreads();
    if (t == 0) {
        for (int w2 = 1; w2 < 8; ++w2) {
            float os = sS[w2];
            int   oi = sI[w2];
            if (os > s || (os == s && oi < idx)) { s = os; idx = oi; }
            any |= sA[w2];
        }
        int start = idx / EE;
        int e = idx - start * EE;
        int end = e + start + MINL - 1;
        int vocab = voc[b * LL * EE + idx];
        out[b]      = s;
        out[16 + b] = (float)start;
        out[32 + b] = (float)end;
        out[48 + b] = any ? 1.0f : 0.0f;
        out[64 + b] = (float)vocab;
    }
}

// ---------------------------------------------------------------------------
extern "C" void kernel_launch(void* const* d_in, const int* in_sizes, int n_in,
                              void* d_out, int out_size, void* d_ws, size_t ws_size,
                              hipStream_t stream) {
    const float* x       = (const float*)d_in[0];   // [16][64][60]
    const float* uf      = (const float*)d_in[1];   // [600][60]
    const float* W       = (const float*)d_in[2];   // [60][256]
    const int*   lengths = (const int*)d_in[3];     // [16]
    const int*   seg     = (const int*)d_in[4];     // [10000][10]
    const int*   vlen    = (const int*)d_in[5];     // [10000]
    float* out = (float*)d_out;
    float* ws  = (float*)d_ws;

    float*        unT = ws + UNT_OFF;
    float*        wnT = ws + WNT_OFF;
    float*        sim = ws + SIM_OFF;
    unsigned int* pk  = (unsigned int*)(ws + PK_OFF);
    float*        val = ws + VAL_OFF;
    int*          voc = (int*)(ws + VOC_OFF);

    k_pack<<<(VV + 255) / 256, 256, 0, stream>>>(seg, vlen, pk);
    k_embed<<<UU + BB * LL, 64, 0, stream>>>(x, uf, W, unT, wnT);
    k_sim<<<256, 512, 0, stream>>>(unT, wnT, sim);
    k_score<<<512, 512, 0, stream>>>(sim, pk, lengths, val, voc);
    k_final<<<BB, 512, 0, stream>>>(val, voc, out);
}